// Round 1
// 187.422 us; speedup vs baseline: 1.0150x; 1.0150x over previous
//
#include <hip/hip_runtime.h>
#include <stdint.h>

#define K_DIM 8192
#define N_DIM 28672
#define NCT   (N_DIM / 128)   // 224 column tiles

typedef _Float16 half8 __attribute__((ext_vector_type(8)));
typedef _Float16 half2t __attribute__((ext_vector_type(2)));
typedef float f32x16 __attribute__((ext_vector_type(16)));

// ---- prep: x f32 [32][8192] -> xp f16 [K/8][32][8] in A-fragment slot order
__global__ __launch_bounds__(256) void prep_x(const float* __restrict__ x,
                                              _Float16* __restrict__ xp) {
  int idx = blockIdx.x * 256 + threadIdx.x;  // 32768 = 1024 word-rows * 32 m
  int m  = idx & 31;
  int k8 = idx >> 5;
  const float* p = x + (size_t)m * K_DIM + (size_t)k8 * 8;
  float4 xa = *(const float4*)p;
  float4 xb = *(const float4*)(p + 4);
  half2t p0 = __builtin_bit_cast(half2t, __builtin_amdgcn_cvt_pkrtz(xa.x, xb.x));
  half2t p1 = __builtin_bit_cast(half2t, __builtin_amdgcn_cvt_pkrtz(xa.y, xb.y));
  half2t p2 = __builtin_bit_cast(half2t, __builtin_amdgcn_cvt_pkrtz(xa.z, xb.z));
  half2t p3 = __builtin_bit_cast(half2t, __builtin_amdgcn_cvt_pkrtz(xa.w, xb.w));
  half8 o;
  o[0] = p0[0]; o[1] = p0[1]; o[2] = p1[0]; o[3] = p1[1];
  o[4] = p2[0]; o[5] = p2[1]; o[6] = p3[0]; o[7] = p3[1];
  *(half8*)(xp + ((size_t)k8 * 32 + m) * 8) = o;
}

__global__ __launch_bounds__(256) void zero_out(float4* __restrict__ out) {
  out[(size_t)blockIdx.x * 256 + threadIdx.x] = float4{0.f, 0.f, 0.f, 0.f};
}

// int4 word -> 8 f16 slots [n0,n4,n1,n5,n2,n6,n3,n7], value (n-8)*s (exact add)
static __device__ __forceinline__ half8 dqs(uint32_t w, half2t sh) {
  const uint32_t M4 = 0x000F000Fu, E = 0x64006400u;
  half2t off; off[0] = (_Float16)(-1032.0f); off[1] = (_Float16)(-1032.0f);
  half2t v0 = (__builtin_bit_cast(half2t, ( w        & M4) | E) + off) * sh;
  half2t v1 = (__builtin_bit_cast(half2t, ((w >> 4)  & M4) | E) + off) * sh;
  half2t v2 = (__builtin_bit_cast(half2t, ((w >> 8)  & M4) | E) + off) * sh;
  half2t v3 = (__builtin_bit_cast(half2t, ((w >> 12) & M4) | E) + off) * sh;
  half8 r;
  r[0] = v0[0]; r[1] = v0[1]; r[2] = v1[0]; r[3] = v1[1];
  r[4] = v2[0]; r[5] = v2[1]; r[6] = v3[0]; r[7] = v3[1];
  return r;
}

static __device__ __forceinline__ void gl_lds16(const void* g, void* l) {
  __builtin_amdgcn_global_load_lds(
      (const __attribute__((address_space(1))) uint32_t*)g,
      (__attribute__((address_space(3))) uint32_t*)l, 16, 0, 0);
}

// gfx9 s_waitcnt imm: vm[3:0]|[15:14], exp[6:4]=7, lgkm[11:8]=15 (no wait)
static __device__ __forceinline__ void waitcnt_vm10() { __builtin_amdgcn_s_waitcnt(0x0F7A); }
static __device__ __forceinline__ void waitcnt_vm0()  { __builtin_amdgcn_s_waitcnt(0x0F70); }

// Block: 256 thr = 4 waves; tile = 128 cols x 1024 k (8 groups of 128 k).
// Q (read-once, one word per consumer thread) goes HBM -> VGPR directly via
// pinned asm loads, 2 groups ahead. A (4x wave reuse) stays LDS-staged via
// global_load_lds, 2 groups ahead, 3 buffers x 8KB = 24KB LDS (4 blocks/CU).
// All VMEM source-order-pinned => steady wait is exactly vmcnt(10)
// (= Q(g+1)*8 + A(g+1)*2 in flight); one barrier per group.
__global__ __launch_bounds__(256, 4) void qgemm(
    const uint32_t* __restrict__ q, const float* __restrict__ scales,
    const float* __restrict__ bias, const _Float16* __restrict__ xp,
    float* __restrict__ out) {
  __shared__ __attribute__((aligned(16))) char smem[3 * 8192];
  const int tid  = threadIdx.x;
  const int w    = tid >> 6;
  const int lane = tid & 63;
  const int h    = lane >> 5;
  const int nl   = lane & 31;
  const int bid  = blockIdx.x;
  // kblk = bid/224: the 8 split-K blocks of a column tile are bids
  // {ct, ct+224, ...}; 224%8==0 -> all land on XCD ct%8 (atomic locality).
  const int kblk = bid / NCT;
  const int ct   = bid - kblk * NCT;
  const int col0 = ct << 7;
  const int wr0  = kblk << 7;           // first word-row of K-slice
  const int colw = col0 + (w << 5);     // wave's 32-col base

  // Preload + convert all 8 group scales first (compiler-tracked loads only
  // ever make later manual waits stricter, never looser — in-order vmcnt).
  half2t sh[8];
#pragma unroll
  for (int g = 0; g < 8; g++) {
    float s = scales[(size_t)(kblk * 8 + g) * N_DIM + colw + nl];
    sh[g] = __builtin_bit_cast(half2t, __builtin_amdgcn_cvt_pkrtz(s, s));
  }
  __builtin_amdgcn_sched_barrier(0);  // pin scale loads/cvts ahead of pipeline

  const uint64_t sb = (uint64_t)(uintptr_t)q +
                      ((uint64_t)wr0 * N_DIM + (uint64_t)col0) * 4u;
  const uint32_t vbase = (uint32_t)(((h * N_DIM) + (w << 5) + nl) * 4);
  const char* xb = (const char*)xp;

  uint32_t qr[3][8];  // 3-deep Q register pipeline (static indices only)

  // 8 pinned direct loads: rows wr0+16g+2i+h, col colw+nl (2x128B lines/inst)
  auto qload = [&](int gg) {
#pragma unroll
    for (int i = 0; i < 8; i++) {
      uint32_t vo = vbase + (uint32_t)(8 * gg + i) * (uint32_t)(2 * N_DIM * 4);
      asm volatile("global_load_dword %0, %1, %2"
                   : "=v"(qr[gg % 3][i])
                   : "v"(vo), "s"(sb));
    }
  };
  // A-tile group gg -> LDS buffer gg%3 (2 x 1KB global_load_lds per wave)
  auto stageA = [&](int gg) {
    char* A = smem + (gg % 3) * 8192;
    size_t ga = (size_t)(wr0 + 16 * gg) * 512 + (size_t)w * 2048 + (size_t)lane * 16;
#pragma unroll
    for (int j = 0; j < 2; j++)
      gl_lds16(xb + ga + j * 1024, A + w * 2048 + j * 1024);
  };

  f32x16 acc;
#pragma unroll
  for (int j = 0; j < 16; j++) acc[j] = 0.0f;

  // prologue queue: [Q0(8) A0(2) Q1(8) A1(2)]
  qload(0); stageA(0); qload(1); stageA(1);

#pragma unroll
  for (int g = 0; g < 8; g++) {
    // g<7: everything except the 10 newest (Q(g+1)+A(g+1)) retired
    if (g < 7) waitcnt_vm10(); else waitcnt_vm0();
    __builtin_amdgcn_s_barrier();          // all waves' A(g) visible in LDS
    __builtin_amdgcn_sched_barrier(0);     // no qr/LDS uses hoist above wait
    if (g + 2 < 8) { qload(g + 2); stageA(g + 2); }
    const char* A = smem + (g % 3) * 8192;
    half2t s = sh[g];
#pragma unroll
    for (int i = 0; i < 8; i++) {
      half8 af = *(const half8*)(A + ((2 * i + h) * 32 + nl) * 16);
      acc = __builtin_amdgcn_mfma_f32_32x32x16_f16(af, dqs(qr[g % 3][i], s),
                                                   acc, 0, 0, 0);
    }
    // no trailing barrier: buffer (g+2)%3 staged above was last read at
    // iter g-1, i.e. before this iteration's barrier — race-free.
  }

  // epilogue: C/D 32x32 layout col=lane&31, row=(reg&3)+8*(reg>>2)+4*(lane>>5)
  float bs = (kblk == 0) ? bias[colw + nl] : 0.0f;
#pragma unroll
  for (int j = 0; j < 16; j++) {
    int row = (j & 3) + ((j >> 2) << 3) + (h << 2);
    unsafeAtomicAdd(&out[(size_t)row * N_DIM + colw + nl], acc[j] + bs);
  }
}

extern "C" void kernel_launch(void* const* d_in, const int* in_sizes, int n_in,
                              void* d_out, int out_size, void* d_ws, size_t ws_size,
                              hipStream_t stream) {
  const float*    xf      = (const float*)d_in[0];
  const uint32_t* qweight = (const uint32_t*)d_in[1];
  const float*    scales  = (const float*)d_in[2];
  const float*    bias    = (const float*)d_in[3];
  float*          out     = (float*)d_out;
  _Float16*       xp      = (_Float16*)d_ws;   // 512 KB scratch

  zero_out<<<dim3(896), dim3(256), 0, stream>>>((float4*)out);
  prep_x<<<dim3(128), dim3(256), 0, stream>>>(xf, xp);
  qgemm<<<dim3(NCT * 8), dim3(256), 0, stream>>>(qweight, scales, bias, xp, out);
}